// Round 13
// baseline (176.012 us; speedup 1.0000x reference)
//
#include <hip/hip_runtime.h>
#include <math.h>

#define NTOK 1024
#define CAP 64

#define LDS_FENCE() asm volatile("s_waitcnt lgkmcnt(0)" ::: "memory")

typedef __bf16 bf16x8 __attribute__((ext_vector_type(8)));
typedef unsigned short u16x8 __attribute__((ext_vector_type(8)));
typedef unsigned short u16x4 __attribute__((ext_vector_type(4)));
typedef float f32x4 __attribute__((ext_vector_type(4)));

__device__ __forceinline__ unsigned short f2bf(float f) {
  unsigned int u = __float_as_uint(f);
  return (unsigned short)((u + 0x7fffu + ((u >> 16) & 1u)) >> 16);
}
__device__ __forceinline__ float bf2f(unsigned short h) {
  return __uint_as_float((unsigned int)h << 16);
}

// B=4, DIM=256, NH=8, HEAD_DIM=32, KEY_DIM=16, QKV_OUT=512, SCALE=0.25

// conv1x1 (R5-proven): block-uniform weights -> scalar loads, no LDS.
// LESSON (R11): weight addressing MUST be wave-uniform (blockIdx-derived).
// VCAST (qkv only): emit bf16 V (vbf) and split-bf16 K in MFMA A-fragment
// layout (kpack): kpack[(b*8+h)][((t*4+g)*16+n16)*8+j], g=0,1: kh d=g*8+j;
// g=2,3: kl d=(g-2)*8+j;  kh=RNE(k), kl=RNE(k-kh).
template<int OC, int OCB, int P, bool RELU, bool VCAST>
__global__ __launch_bounds__(256) void conv1x1_kernel(const float* __restrict__ in,
    const float* __restrict__ w, const float* __restrict__ bias, float* __restrict__ out,
    unsigned short* __restrict__ vbf, unsigned short* __restrict__ kpack) {
  constexpr int PB = NTOK / (256 * P);
  int bid = blockIdx.x;
  const int pb = bid % PB; bid /= PB;
  const int ocb = bid % (OC / OCB); const int b = bid / (OC / OCB);
  const int tid = threadIdx.x;
  const int p0 = pb * 256 * P + tid * P;
  const float* inb = in + (size_t)b * 256 * NTOK + p0;
  const float* wrow = w + (size_t)ocb * OCB * 256;

  float acc[OCB][P];
  #pragma unroll
  for (int j = 0; j < OCB; j++)
    #pragma unroll
    for (int i = 0; i < P; i++) acc[j][i] = 0.f;

  #pragma unroll 2
  for (int c0 = 0; c0 < 256; c0 += 4) {
    float4 wl[OCB];
    #pragma unroll
    for (int j = 0; j < OCB; j++) wl[j] = *(const float4*)&wrow[j * 256 + c0];  // uniform -> SGPR
    #pragma unroll
    for (int cc = 0; cc < 4; cc++) {
      float xr[P];
      if constexpr (P == 4) {
        float4 t = *(const float4*)&inb[(size_t)(c0 + cc) * NTOK];
        xr[0] = t.x; xr[1] = t.y; xr[2] = t.z; xr[3] = t.w;
      } else if constexpr (P == 2) {
        float2 t = *(const float2*)&inb[(size_t)(c0 + cc) * NTOK];
        xr[0] = t.x; xr[1] = t.y;
      } else {
        xr[0] = inb[(size_t)(c0 + cc) * NTOK];
      }
      #pragma unroll
      for (int j = 0; j < OCB; j++) {
        const float wjc = ((const float*)&wl[j])[cc];
        #pragma unroll
        for (int i = 0; i < P; i++) acc[j][i] = fmaf(wjc, xr[i], acc[j][i]);
      }
    }
  }
  #pragma unroll
  for (int j = 0; j < OCB; j++) {
    const int oc = ocb * OCB + j;
    const float bv = bias[oc];
    float r[P];
    #pragma unroll
    for (int i = 0; i < P; i++) {
      float v = acc[j][i] + bv;
      if (RELU) v = fmaxf(v, 0.f);
      r[i] = v;
    }
    float* op = out + ((size_t)b * OC + oc) * NTOK + p0;
    if constexpr (P == 4) *(float4*)op = make_float4(r[0], r[1], r[2], r[3]);
    else if constexpr (P == 2) *(float2*)op = make_float2(r[0], r[1]);
    else *op = r[0];
    if constexpr (VCAST) {
      const int c63 = oc & 63;
      if (c63 >= 32) {
        const int c = (oc >> 6) * 32 + c63 - 32;
        unsigned short* vp = vbf + ((size_t)b * 256 + c) * NTOK + p0;
        #pragma unroll
        for (int i = 0; i < P; i++) vp[i] = f2bf(r[i]);
      } else if (c63 >= 16) {
        const int h = oc >> 6, d = c63 - 16;
        const int gh = d >> 3, jj = d & 7;
        unsigned short* kb = kpack + (size_t)(b * 8 + h) * 32768;
        #pragma unroll
        for (int i = 0; i < P; i++) {
          const int n = p0 + i;
          const int t = n >> 4, n16 = n & 15;
          const unsigned short hv = f2bf(r[i]);
          const unsigned short lv = f2bf(r[i] - bf2f(hv));
          kb[((t * 4 + gh) * 16 + n16) * 8 + jj]     = hv;
          kb[((t * 4 + gh + 2) * 16 + n16) * 8 + jj] = lv;
        }
      }
    }
  }
}

// g2 = sigmoid(g2_w . relu_g1 + g2_b), deterministic fp64 block partial sums
__global__ __launch_bounds__(256) void gate2_kernel(const float* __restrict__ gx,
    const float* __restrict__ g2_w, const float* __restrict__ g2_b, double* __restrict__ part) {
  const int idx = blockIdx.x * 256 + threadIdx.x;
  const int b = idx >> 10, p = idx & 1023;
  float acc = g2_b[0];
  const float* gb = gx + (size_t)b * 128 * NTOK + p;
  #pragma unroll 4
  for (int j = 0; j < 128; j++) acc = fmaf(g2_w[j], gb[(size_t)j * NTOK], acc);
  float g = 1.f / (1.f + expf(-acc));
  __shared__ double red[256];
  red[threadIdx.x] = (double)g;
  __syncthreads();
  for (int s = 128; s > 0; s >>= 1) {
    if (threadIdx.x < s) red[threadIdx.x] += red[threadIdx.x + s];
    __syncthreads();
  }
  if (threadIdx.x == 0) part[blockIdx.x] = red[0];
}

// Attention: one block = 8 query rows of one (b,h), 512 threads, 1 row PER
// WAVE. Logits via MFMA with error-free split-bf16 (q'=0.25q, k split to
// hi/lo; D = A[kh|kl]*B[qh|qh] + A*B[ql|ql] = 0.25*q.k to ~2^-17 rel).
// Fragment mapping identical to the proven PV pattern. dyn_k inline from
// gate partials. Exact top-dyn_k: 2-level 64-bin value radix -> boundary
// (value,index); keep = v>Bv || (v==Bv && n<=Bn) [stable-argsort tie rule].
// PV via mfma_f32_16x16x32_bf16. NOTE (R8 A/B): single-pass selection
// (O(m)~40 serial rank) costs +28us vs 2-pass — keep 2-pass.
__global__ __launch_bounds__(512) void attn_kernel(const float* __restrict__ qkv,
    const unsigned short* __restrict__ vbf, const unsigned short* __restrict__ kpack,
    const double* __restrict__ part, float* __restrict__ out_attn) {
  const int tid = threadIdx.x;
  const int lane = tid & 63, wv = tid >> 6;
  int bid = blockIdx.x;
  const int mb = bid & 127; bid >>= 7;
  const int h = bid & 7; const int b = bid >> 3;

  double dsum = 0.0;
  #pragma unroll
  for (int i = 0; i < 16; i++) dsum += part[i];
  int dk = (int)floor(1024.0 * (dsum / 4096.0));
  const int dyn_k = dk < 1 ? 1 : (dk > NTOK ? NTOK : dk);

  const float* base = qkv + (size_t)(b * 512 + h * 64) * NTOK;

  __shared__ union RowU { float f[1028]; unsigned short pa[1032]; } rows[8];
  __shared__ float invs[8];
  __shared__ union UU {
    struct { unsigned short qsh[16][16]; unsigned short qsl[16][16]; } qstage;
    struct {
      int hist[8][64];
      int cnt[8];
      float Bv[8]; int Bn[8];
      struct { float v; int n; } cand[8][CAP];
    } sel;
    float pvred[2][4][8][17];
  } u;

  // ---- stage split Q (scaled by 0.25) into B-fragment-ready LDS ----
  if (tid < 128) {
    const int d = tid >> 3, r8 = tid & 7;
    const float qv = base[(size_t)d * NTOK + mb * 8 + r8] * 0.25f;
    const unsigned short hv = f2bf(qv);
    u.qstage.qsh[r8][d] = hv;
    u.qstage.qsl[r8][d] = f2bf(qv - bf2f(hv));
  } else if (tid < 256) {
    const int d = (tid - 128) >> 3, r8 = (tid - 128) & 7;
    u.qstage.qsh[8 + r8][d] = 0;
    u.qstage.qsl[8 + r8][d] = 0;
  }
  __syncthreads();

  // ---- logits via MFMA: rows[r].f[n] = 0.25 * q[.,r] . k[.,n] ----
  {
    const unsigned short* kb = kpack + (size_t)(b * 8 + h) * 32768;
    const int g = lane >> 4, m16 = lane & 15;
    bf16x8 B1 = __builtin_bit_cast(bf16x8, *(const u16x8*)&u.qstage.qsh[m16][(g & 1) * 8]);
    bf16x8 B2 = __builtin_bit_cast(bf16x8, *(const u16x8*)&u.qstage.qsl[m16][(g & 1) * 8]);
    #pragma unroll
    for (int i = 0; i < 8; i++) {
      const int t = wv * 8 + i;
      bf16x8 A = __builtin_bit_cast(bf16x8, *(const u16x8*)&kb[((t * 4 + g) * 16 + m16) * 8]);
      f32x4 acc = {0.f, 0.f, 0.f, 0.f};
      acc = __builtin_amdgcn_mfma_f32_16x16x32_bf16(A, B1, acc, 0, 0, 0);
      acc = __builtin_amdgcn_mfma_f32_16x16x32_bf16(A, B2, acc, 0, 0, 0);
      if (m16 < 8)
        *(f32x4*)&rows[m16].f[t * 16 + g * 4] = acc;
    }
  }
  __syncthreads();   // logits ready; qstage dead -> sel region live

  // ---- wave-local selection + softmax: wave wv owns row wv ----
  {
    const int r = wv;
    float* smrow = rows[r].f;
    float v[16];
    {
      float4 f0 = ((const float4*)smrow)[lane];
      float4 f1 = ((const float4*)smrow)[64 + lane];
      float4 f2 = ((const float4*)smrow)[128 + lane];
      float4 f3 = ((const float4*)smrow)[192 + lane];
      v[0]=f0.x; v[1]=f0.y; v[2]=f0.z; v[3]=f0.w;
      v[4]=f1.x; v[5]=f1.y; v[6]=f1.z; v[7]=f1.w;
      v[8]=f2.x; v[9]=f2.y; v[10]=f2.z; v[11]=f2.w;
      v[12]=f3.x; v[13]=f3.y; v[14]=f3.z; v[15]=f3.w;
    }
    float mn = v[0], mx = v[0];
    #pragma unroll
    for (int i = 1; i < 16; i++) { mn = fminf(mn, v[i]); mx = fmaxf(mx, v[i]); }
    #pragma unroll
    for (int off = 32; off > 0; off >>= 1) {
      mn = fminf(mn, __shfl_xor(mn, off));
      mx = fmaxf(mx, __shfl_xor(mx, off));
    }

    unsigned int keepmask = 0xFFFFu;
    if (dyn_k < NTOK) {
      float Bv = mx; int Bn = dyn_k - 1;        // degenerate (all-equal) default
      const float range = mx - mn;
      const bool fine = (range > 0.f);
      int m = 0;
      if (fine) {
        const float s1 = 64.0f / range;
        // pass 1: 64 bins over [mn,mx]
        u.sel.hist[wv][lane] = 0;
        LDS_FENCE();
        int idx1[16];
        #pragma unroll
        for (int i = 0; i < 16; i++) {
          int ix = (int)((v[i] - mn) * s1);
          ix = ix < 0 ? 0 : (ix > 63 ? 63 : ix);
          idx1[i] = ix;
          atomicAdd(&u.sel.hist[wv][ix], 1);
        }
        LDS_FENCE();
        int cum = u.sel.hist[wv][lane];
        #pragma unroll
        for (int off = 1; off < 64; off <<= 1) {
          int o = __shfl_down(cum, off);
          if (lane + off < 64) cum += o;
        }
        int cumNext = __shfl_down(cum, 1);
        if (lane == 63) cumNext = 0;
        unsigned long long bal = __ballot(cum >= dyn_k && cumNext < dyn_k);
        const int t = (int)__builtin_ctzll(bal);
        const int k2 = dyn_k - __shfl(cumNext, t);
        // pass 2: 64 sub-bins within bin t
        const float binw = range * (1.0f / 64.0f);
        const float lo = mn + (float)t * binw;
        float s2 = 4096.0f / range;
        if (!(s2 < 3.0e38f)) s2 = 0.f;
        u.sel.hist[wv][lane] = 0;
        LDS_FENCE();
        #pragma unroll
        for (int i = 0; i < 16; i++) {
          if (idx1[i] == t) {
            int ix = (int)((v[i] - lo) * s2);
            ix = ix < 0 ? 0 : (ix > 63 ? 63 : ix);
            atomicAdd(&u.sel.hist[wv][ix], 1);
          }
        }
        LDS_FENCE();
        cum = u.sel.hist[wv][lane];
        #pragma unroll
        for (int off = 1; off < 64; off <<= 1) {
          int o = __shfl_down(cum, off);
          if (lane + off < 64) cum += o;
        }
        cumNext = __shfl_down(cum, 1);
        if (lane == 63) cumNext = 0;
        bal = __ballot(cum >= k2 && cumNext < k2);
        const int t2 = (int)__builtin_ctzll(bal);
        const int k3 = k2 - __shfl(cumNext, t2);
        // collect candidates in sub-bin (t,t2)
        if (lane == 0) u.sel.cnt[wv] = 0;
        LDS_FENCE();
        #pragma unroll
        for (int i = 0; i < 16; i++) {
          if (idx1[i] == t) {
            int ix = (int)((v[i] - lo) * s2);
            ix = ix < 0 ? 0 : (ix > 63 ? 63 : ix);
            if (ix == t2) {
              int p = atomicAdd(&u.sel.cnt[wv], 1);
              if (p < CAP) { u.sel.cand[wv][p].v = v[i]; u.sel.cand[wv][p].n = (i >> 2) * 256 + lane * 4 + (i & 3); }
            }
          }
        }
        LDS_FENCE();
        m = u.sel.cnt[wv];
        if (m <= CAP) {
          // exact boundary element: rank k3-1 among candidates (value desc, idx asc)
          for (int ii = lane; ii < m; ii += 64) {
            float cv = u.sel.cand[wv][ii].v; int cn = u.sel.cand[wv][ii].n;
            int rk = 0;
            for (int j = 0; j < m; j++) {
              float ov = u.sel.cand[wv][j].v; int on = u.sel.cand[wv][j].n;
              rk += ((ov > cv) || (ov == cv && on < cn)) ? 1 : 0;
            }
            if (rk == k3 - 1) { u.sel.Bv[wv] = cv; u.sel.Bn[wv] = cn; }
          }
          LDS_FENCE();
          Bv = u.sel.Bv[wv]; Bn = u.sel.Bn[wv];
        }
      }
      if (fine && m > CAP) {
        // exact fallback: brute-force rank vs whole row (never on smooth data)
        keepmask = 0u;
        #pragma unroll
        for (int i = 0; i < 16; i++) {
          const int n_i = (i >> 2) * 256 + lane * 4 + (i & 3);
          const float vi = v[i];
          int rk = 0;
          for (int j = 0; j < NTOK; j++) {
            float ov = smrow[j];
            rk += ((ov > vi) || (ov == vi && j < n_i)) ? 1 : 0;
          }
          if (rk < dyn_k) keepmask |= (1u << i);
        }
      } else {
        keepmask = 0u;
        #pragma unroll
        for (int i = 0; i < 16; i++) {
          const int n_i = (i >> 2) * 256 + lane * 4 + (i & 3);
          if ((v[i] > Bv) || (v[i] == Bv && n_i <= Bn)) keepmask |= (1u << i);
        }
      }
    }
    // softmax (row max mx is always kept: rank 0 < dyn_k)
    float e[16]; float s = 0.f;
    #pragma unroll
    for (int i = 0; i < 16; i++) {
      e[i] = ((keepmask >> i) & 1u) ? __expf(v[i] - mx) : 0.f;
      s += e[i];
    }
    #pragma unroll
    for (int off = 32; off > 0; off >>= 1) s += __shfl_xor(s, off);
    if (lane == 0) invs[r] = 1.f / s;
    // write bf16 P in-place (this wave owns row r; PV reads after barrier)
    #pragma unroll
    for (int j = 0; j < 4; j++) {
      u16x4 w4 = { f2bf(e[4*j]), f2bf(e[4*j+1]), f2bf(e[4*j+2]), f2bf(e[4*j+3]) };
      *(u16x4*)&rows[r].pa[j * 256 + lane * 4] = w4;
    }
  }
  __syncthreads();

  // ---- PV via MFMA: out[8x32] = P[8x1024].V^T; 4 k-slices x 2 d-tiles ----
  {
    const int g = lane >> 4;                 // k-group 0..3
    const int m16 = lane & 15;
    const int ksl = wv & 3, dt = wv >> 2;
    const unsigned short* vrow = vbf + ((size_t)(b * 256 + h * 32 + dt * 16 + m16)) * NTOK;
    const unsigned short* parow = rows[lane & 7].pa;   // A rows 8..15 dup rows 0..7 (C rows 8..15 unused)
    f32x4 acc = {0.f, 0.f, 0.f, 0.f};
    const int nb = ksl * 256;
    #pragma unroll
    for (int ks = 0; ks < 8; ks++) {
      const int n0 = nb + ks * 32 + g * 8;
      bf16x8 a  = __builtin_bit_cast(bf16x8, *(const u16x8*)&parow[n0]);
      bf16x8 b0 = __builtin_bit_cast(bf16x8, *(const u16x8*)&vrow[n0]);
      acc = __builtin_amdgcn_mfma_f32_16x16x32_bf16(a, b0, acc, 0, 0, 0);
    }
    if (g < 2) {
      #pragma unroll
      for (int q = 0; q < 4; q++)
        u.pvred[dt][ksl][g * 4 + q][m16] = acc[q];
    }
  }
  __syncthreads();
  if (tid < 256) {
    const int r2 = tid & 7, d2 = tid >> 3;
    const int dt = d2 >> 4, m16 = d2 & 15;
    float s = u.pvred[dt][0][r2][m16] + u.pvred[dt][1][r2][m16]
            + u.pvred[dt][2][r2][m16] + u.pvred[dt][3][r2][m16];
    s *= invs[r2];
    out_attn[(size_t)(b * 256 + h * 32 + d2) * NTOK + mb * 8 + r2] = s;
  }
}

// depthwise 3x3 conv on v image + bias, fused add of attention output.
// 4 consecutive x-positions per thread with stencil reuse; OOB taps are 0.0f
// operands (fmaf(w,0,s)==s exactly) -> bit-identical to skip-logic.
__global__ __launch_bounds__(256) void pe_kernel(const float* __restrict__ qkv,
    const float* __restrict__ oattn, const float* __restrict__ pe_w,
    const float* __restrict__ pe_b, float* __restrict__ tmp) {
  int bid = blockIdx.x;
  const int c = bid & 255; const int b = bid >> 8;
  const int oc = ((c >> 5) * 64) + 32 + (c & 31);   // v channel within qkv layout
  const float* vimg = qkv + (size_t)(b * 512 + oc) * NTOK;
  float wloc[9];
  #pragma unroll
  for (int i = 0; i < 9; i++) wloc[i] = pe_w[c * 9 + i];
  const float bv = pe_b[c];
  const int t = threadIdx.x;
  const int p0 = t * 4;
  const int y = p0 >> 5, x0 = p0 & 31;
  float win[3][6];
  #pragma unroll
  for (int dy = -1; dy <= 1; dy++) {
    const int yy = y + dy;
    float* wr = win[dy + 1];
    if (yy < 0 || yy > 31) {
      #pragma unroll
      for (int i = 0; i < 6; i++) wr[i] = 0.f;
    } else {
      const float* vr = vimg + yy * 32;
      wr[0] = (x0 > 0) ? vr[x0 - 1] : 0.f;
      const float4 mid = *(const float4*)&vr[x0];
      wr[1] = mid.x; wr[2] = mid.y; wr[3] = mid.z; wr[4] = mid.w;
      wr[5] = (x0 < 28) ? vr[x0 + 4] : 0.f;
    }
  }
  const float4 oa = *(const float4*)(oattn + (size_t)(b * 256 + c) * NTOK + p0);
  float r[4];
  #pragma unroll
  for (int i = 0; i < 4; i++) {
    float s = bv;
    #pragma unroll
    for (int dy = 0; dy < 3; dy++) {
      s = fmaf(wloc[dy * 3 + 0], win[dy][i], s);
      s = fmaf(wloc[dy * 3 + 1], win[dy][i + 1], s);
      s = fmaf(wloc[dy * 3 + 2], win[dy][i + 2], s);
    }
    r[i] = s;
  }
  float4 o = make_float4(r[0] + oa.x, r[1] + oa.y, r[2] + oa.z, r[3] + oa.w);
  *(float4*)(tmp + (size_t)(b * 256 + c) * NTOK + p0) = o;
}

extern "C" void kernel_launch(void* const* d_in, const int* in_sizes, int n_in,
                              void* d_out, int out_size, void* d_ws, size_t ws_size,
                              hipStream_t stream) {
  const float* x      = (const float*)d_in[0];
  const float* qkv_w  = (const float*)d_in[1];
  const float* qkv_b  = (const float*)d_in[2];
  const float* proj_w = (const float*)d_in[3];
  const float* proj_b = (const float*)d_in[4];
  const float* pe_w   = (const float*)d_in[5];
  const float* pe_b   = (const float*)d_in[6];
  const float* g1_w   = (const float*)d_in[7];
  const float* g1_b   = (const float*)d_in[8];
  const float* g2_w   = (const float*)d_in[9];
  const float* g2_b   = (const float*)d_in[10];
  float* out = (float*)d_out;

  char* ws = (char*)d_ws;
  float*  qkvb  = (float*)(ws);                          // 8 MB
  float*  oattn = (float*)(ws + (8u << 20));             // 4 MB
  float*  tmp   = (float*)(ws + (12u << 20));            // 4 MB (pe output)
  // kpack aliases tmp[0..2MB): written by qkv conv, read by attn,
  // dead before pe writes tmp (stream-ordered).
  unsigned short* kpack = (unsigned short*)(ws + (12u << 20));  // 2 MB split-bf16 K
  float*  gx    = (float*)(ws + (16u << 20));            // 2 MB (gate hidden)
  // vbf aliases gx: gx dead after gate2 (stream-ordered before qkv conv writes)
  unsigned short* vbf = (unsigned short*)(ws + (16u << 20));   // 2 MB bf16 V
  double* part  = (double*)(ws + (18u << 20));           // 16 doubles

  // gate path -> partials (dyn_k computed inside attn)  [R10-proven]
  conv1x1_kernel<128, 2, 2, true, false><<<512, 256, 0, stream>>>(x, g1_w, g1_b, gx, nullptr, nullptr);
  gate2_kernel<<<16, 256, 0, stream>>>(gx, g2_w, g2_b, part);
  // qkv (+ fused bf16 V cast + split-bf16 K pack); OCB=8
  conv1x1_kernel<512, 8, 2, false, true><<<512, 256, 0, stream>>>(x, qkv_w, qkv_b, qkvb, vbf, kpack);
  // attention (MFMA split-bf16 logits, exact top-dyn_k, MFMA PV)
  attn_kernel<<<4096, 512, 0, stream>>>(qkvb, vbf, kpack, part, oattn);
  // depthwise PE conv + add (vectorized stencil); overwrites kpack region
  pe_kernel<<<1024, 256, 0, stream>>>(qkvb, oattn, pe_w, pe_b, tmp);
  // final projection
  conv1x1_kernel<256, 4, 2, false, false><<<512, 256, 0, stream>>>(tmp, proj_w, proj_b, out, nullptr, nullptr);
}

// Round 14
// 147.077 us; speedup vs baseline: 1.1967x; 1.1967x over previous
//
#include <hip/hip_runtime.h>
#include <math.h>

#define NTOK 1024
#define CAP 64

#define LDS_FENCE() asm volatile("s_waitcnt lgkmcnt(0)" ::: "memory")

typedef __bf16 bf16x8 __attribute__((ext_vector_type(8)));
typedef unsigned short u16x8 __attribute__((ext_vector_type(8)));
typedef unsigned short u16x4 __attribute__((ext_vector_type(4)));
typedef float f32x4 __attribute__((ext_vector_type(4)));

__device__ __forceinline__ unsigned short f2bf(float f) {
  unsigned int u = __float_as_uint(f);
  return (unsigned short)((u + 0x7fffu + ((u >> 16) & 1u)) >> 16);
}

// B=4, DIM=256, NH=8, HEAD_DIM=32, KEY_DIM=16, QKV_OUT=512, SCALE=0.25

// conv1x1 body (R5-proven): block-uniform weights -> scalar loads, no LDS.
// LESSON (R11): weight addressing MUST be wave-uniform (blockIdx-derived).
// LESSON (R13): don't trade VALU-issue work for longer latency chains.
template<int OC, int OCB, int P, bool RELU, bool VCAST>
__device__ __forceinline__ void conv_body(const float* __restrict__ in,
    const float* __restrict__ w, const float* __restrict__ bias, float* __restrict__ out,
    unsigned short* __restrict__ vbf, int bid, int tid) {
  constexpr int PB = NTOK / (256 * P);
  const int pb = bid % PB; bid /= PB;
  const int ocb = bid % (OC / OCB); const int b = bid / (OC / OCB);
  const int p0 = pb * 256 * P + tid * P;
  const float* inb = in + (size_t)b * 256 * NTOK + p0;
  const float* wrow = w + (size_t)ocb * OCB * 256;

  float acc[OCB][P];
  #pragma unroll
  for (int j = 0; j < OCB; j++)
    #pragma unroll
    for (int i = 0; i < P; i++) acc[j][i] = 0.f;

  #pragma unroll 2
  for (int c0 = 0; c0 < 256; c0 += 4) {
    float4 wl[OCB];
    #pragma unroll
    for (int j = 0; j < OCB; j++) wl[j] = *(const float4*)&wrow[j * 256 + c0];  // uniform -> SGPR
    #pragma unroll
    for (int cc = 0; cc < 4; cc++) {
      float xr[P];
      if constexpr (P == 4) {
        float4 t = *(const float4*)&inb[(size_t)(c0 + cc) * NTOK];
        xr[0] = t.x; xr[1] = t.y; xr[2] = t.z; xr[3] = t.w;
      } else if constexpr (P == 2) {
        float2 t = *(const float2*)&inb[(size_t)(c0 + cc) * NTOK];
        xr[0] = t.x; xr[1] = t.y;
      } else {
        xr[0] = inb[(size_t)(c0 + cc) * NTOK];
      }
      #pragma unroll
      for (int j = 0; j < OCB; j++) {
        const float wjc = ((const float*)&wl[j])[cc];
        #pragma unroll
        for (int i = 0; i < P; i++) acc[j][i] = fmaf(wjc, xr[i], acc[j][i]);
      }
    }
  }
  #pragma unroll
  for (int j = 0; j < OCB; j++) {
    const int oc = ocb * OCB + j;
    const float bv = bias[oc];
    float r[P];
    #pragma unroll
    for (int i = 0; i < P; i++) {
      float v = acc[j][i] + bv;
      if (RELU) v = fmaxf(v, 0.f);
      r[i] = v;
    }
    float* op = out + ((size_t)b * OC + oc) * NTOK + p0;
    if constexpr (P == 4) *(float4*)op = make_float4(r[0], r[1], r[2], r[3]);
    else if constexpr (P == 2) *(float2*)op = make_float2(r[0], r[1]);
    else *op = r[0];
    if constexpr (VCAST) {
      if ((oc & 63) >= 32) {
        const int c = (oc >> 6) * 32 + (oc & 63) - 32;
        unsigned short* vp = vbf + ((size_t)b * 256 + c) * NTOK + p0;
        #pragma unroll
        for (int i = 0; i < P; i++) vp[i] = f2bf(r[i]);
      }
    }
  }
}

template<int OC, int OCB, int P, bool RELU, bool VCAST>
__global__ __launch_bounds__(256) void conv1x1_kernel(const float* __restrict__ in,
    const float* __restrict__ w, const float* __restrict__ bias, float* __restrict__ out,
    unsigned short* __restrict__ vbf) {
  conv_body<OC, OCB, P, RELU, VCAST>(in, w, bias, out, vbf, blockIdx.x, threadIdx.x);
}

// Combined qkv + gate1 conv: blocks [0,512) do qkv (OC512,OCB8,P2, V-cast),
// blocks [512,640) do gate1 (OC128,OCB8,P2, RELU). Branch is block-uniform,
// weight bases stay wave-uniform. gate1 fmaf chain per oc identical to the
// standalone conv -> bit-identical gx.
__global__ __launch_bounds__(256) void qkv_gate1_kernel(const float* __restrict__ x,
    const float* __restrict__ qkv_w, const float* __restrict__ qkv_b, float* __restrict__ qkvb,
    unsigned short* __restrict__ vbf,
    const float* __restrict__ g1_w, const float* __restrict__ g1_b, float* __restrict__ gx) {
  const int bid = blockIdx.x;
  if (bid < 512)
    conv_body<512, 8, 2, false, true>(x, qkv_w, qkv_b, qkvb, vbf, bid, threadIdx.x);
  else
    conv_body<128, 8, 2, true, false>(x, g1_w, g1_b, gx, nullptr, bid - 512, threadIdx.x);
}

// g2 = sigmoid(g2_w . relu_g1 + g2_b), deterministic fp64 block partial sums
__global__ __launch_bounds__(256) void gate2_kernel(const float* __restrict__ gx,
    const float* __restrict__ g2_w, const float* __restrict__ g2_b, double* __restrict__ part) {
  const int idx = blockIdx.x * 256 + threadIdx.x;
  const int b = idx >> 10, p = idx & 1023;
  float acc = g2_b[0];
  const float* gb = gx + (size_t)b * 128 * NTOK + p;
  #pragma unroll 4
  for (int j = 0; j < 128; j++) acc = fmaf(g2_w[j], gb[(size_t)j * NTOK], acc);
  float g = 1.f / (1.f + expf(-acc));
  __shared__ double red[256];
  red[threadIdx.x] = (double)g;
  __syncthreads();
  for (int s = 128; s > 0; s >>= 1) {
    if (threadIdx.x < s) red[threadIdx.x] += red[threadIdx.x + s];
    __syncthreads();
  }
  if (threadIdx.x == 0) part[blockIdx.x] = red[0];
}

// Attention (R12/R10-proven, verbatim): one block = 8 query rows of one (b,h),
// 512 threads, 1 row PER WAVE. Q reads wave-uniform -> s_load/SGPR. dyn_k
// inline from gate partials (fixed serial fp64 order). Exact top-dyn_k:
// 2-level 64-bin value radix -> boundary (value,index); keep = v>Bv ||
// (v==Bv && n<=Bn) [stable-argsort tie rule]. PV via mfma_f32_16x16x32_bf16.
// NOTE (R8): single-pass selection (O(m)~40 serial rank) costs +28us.
// NOTE (R13): MFMA logits (split-bf16) cost +7us — latency chain beats
// the VALU-issue savings. Keep scalar-Q fp32 logits.
__global__ __launch_bounds__(512) void attn_kernel(const float* __restrict__ qkv,
    const unsigned short* __restrict__ vbf,
    const double* __restrict__ part, float* __restrict__ out_attn) {
  const int tid = threadIdx.x;
  const int lane = tid & 63, wv = tid >> 6;
  int bid = blockIdx.x;
  const int mb = bid & 127; bid >>= 7;
  const int h = bid & 7; const int b = bid >> 3;

  double dsum = 0.0;
  #pragma unroll
  for (int i = 0; i < 16; i++) dsum += part[i];
  int dk = (int)floor(1024.0 * (dsum / 4096.0));
  const int dyn_k = dk < 1 ? 1 : (dk > NTOK ? NTOK : dk);

  const float* base = qkv + (size_t)(b * 512 + h * 64) * NTOK;

  __shared__ union RowU { float f[1028]; unsigned short pa[1032]; } rows[8];
  __shared__ float invs[8];
  __shared__ union UU {
    struct {
      int hist[8][64];
      int cnt[8];
      float Bv[8]; int Bn[8];
      struct { float v; int n; } cand[8][CAP];
    } sel;
    float pvred[2][4][8][17];
  } u;

  // ---- logits: thread computes n = 2*tid, 2*tid+1 for all 8 rows ----
  {
    const float2* k2 = (const float2*)(base + 16 * NTOK);
    const float* qb = base + mb * 8;          // q[d][r] at qb[d*NTOK + r]
    float a0[8], a1[8];
    #pragma unroll
    for (int r = 0; r < 8; r++) { a0[r] = 0.f; a1[r] = 0.f; }
    #pragma unroll
    for (int d = 0; d < 16; d++) {
      float2 kk = k2[d * 512 + tid];
      #pragma unroll
      for (int r = 0; r < 8; r++) {
        const float qv = qb[(size_t)d * NTOK + r];   // uniform -> s_load
        a0[r] = fmaf(qv, kk.x, a0[r]);
        a1[r] = fmaf(qv, kk.y, a1[r]);
      }
    }
    #pragma unroll
    for (int r = 0; r < 8; r++)
      ((float2*)rows[r].f)[tid] = make_float2(a0[r] * 0.25f, a1[r] * 0.25f);
  }
  __syncthreads();   // logits ready

  // ---- wave-local selection + softmax: wave wv owns row wv ----
  {
    const int r = wv;
    float* smrow = rows[r].f;
    float v[16];
    {
      float4 f0 = ((const float4*)smrow)[lane];
      float4 f1 = ((const float4*)smrow)[64 + lane];
      float4 f2 = ((const float4*)smrow)[128 + lane];
      float4 f3 = ((const float4*)smrow)[192 + lane];
      v[0]=f0.x; v[1]=f0.y; v[2]=f0.z; v[3]=f0.w;
      v[4]=f1.x; v[5]=f1.y; v[6]=f1.z; v[7]=f1.w;
      v[8]=f2.x; v[9]=f2.y; v[10]=f2.z; v[11]=f2.w;
      v[12]=f3.x; v[13]=f3.y; v[14]=f3.z; v[15]=f3.w;
    }
    float mn = v[0], mx = v[0];
    #pragma unroll
    for (int i = 1; i < 16; i++) { mn = fminf(mn, v[i]); mx = fmaxf(mx, v[i]); }
    #pragma unroll
    for (int off = 32; off > 0; off >>= 1) {
      mn = fminf(mn, __shfl_xor(mn, off));
      mx = fmaxf(mx, __shfl_xor(mx, off));
    }

    unsigned int keepmask = 0xFFFFu;
    if (dyn_k < NTOK) {
      float Bv = mx; int Bn = dyn_k - 1;        // degenerate (all-equal) default
      const float range = mx - mn;
      const bool fine = (range > 0.f);
      int m = 0;
      if (fine) {
        const float s1 = 64.0f / range;
        // pass 1: 64 bins over [mn,mx]
        u.sel.hist[wv][lane] = 0;
        LDS_FENCE();
        int idx1[16];
        #pragma unroll
        for (int i = 0; i < 16; i++) {
          int ix = (int)((v[i] - mn) * s1);
          ix = ix < 0 ? 0 : (ix > 63 ? 63 : ix);
          idx1[i] = ix;
          atomicAdd(&u.sel.hist[wv][ix], 1);
        }
        LDS_FENCE();
        int cum = u.sel.hist[wv][lane];
        #pragma unroll
        for (int off = 1; off < 64; off <<= 1) {
          int o = __shfl_down(cum, off);
          if (lane + off < 64) cum += o;
        }
        int cumNext = __shfl_down(cum, 1);
        if (lane == 63) cumNext = 0;
        unsigned long long bal = __ballot(cum >= dyn_k && cumNext < dyn_k);
        const int t = (int)__builtin_ctzll(bal);
        const int k2 = dyn_k - __shfl(cumNext, t);
        // pass 2: 64 sub-bins within bin t
        const float binw = range * (1.0f / 64.0f);
        const float lo = mn + (float)t * binw;
        float s2 = 4096.0f / range;
        if (!(s2 < 3.0e38f)) s2 = 0.f;
        u.sel.hist[wv][lane] = 0;
        LDS_FENCE();
        #pragma unroll
        for (int i = 0; i < 16; i++) {
          if (idx1[i] == t) {
            int ix = (int)((v[i] - lo) * s2);
            ix = ix < 0 ? 0 : (ix > 63 ? 63 : ix);
            atomicAdd(&u.sel.hist[wv][ix], 1);
          }
        }
        LDS_FENCE();
        cum = u.sel.hist[wv][lane];
        #pragma unroll
        for (int off = 1; off < 64; off <<= 1) {
          int o = __shfl_down(cum, off);
          if (lane + off < 64) cum += o;
        }
        cumNext = __shfl_down(cum, 1);
        if (lane == 63) cumNext = 0;
        bal = __ballot(cum >= k2 && cumNext < k2);
        const int t2 = (int)__builtin_ctzll(bal);
        const int k3 = k2 - __shfl(cumNext, t2);
        // collect candidates in sub-bin (t,t2)
        if (lane == 0) u.sel.cnt[wv] = 0;
        LDS_FENCE();
        #pragma unroll
        for (int i = 0; i < 16; i++) {
          if (idx1[i] == t) {
            int ix = (int)((v[i] - lo) * s2);
            ix = ix < 0 ? 0 : (ix > 63 ? 63 : ix);
            if (ix == t2) {
              int p = atomicAdd(&u.sel.cnt[wv], 1);
              if (p < CAP) { u.sel.cand[wv][p].v = v[i]; u.sel.cand[wv][p].n = (i >> 2) * 256 + lane * 4 + (i & 3); }
            }
          }
        }
        LDS_FENCE();
        m = u.sel.cnt[wv];
        if (m <= CAP) {
          // exact boundary element: rank k3-1 among candidates (value desc, idx asc)
          for (int ii = lane; ii < m; ii += 64) {
            float cv = u.sel.cand[wv][ii].v; int cn = u.sel.cand[wv][ii].n;
            int rk = 0;
            for (int j = 0; j < m; j++) {
              float ov = u.sel.cand[wv][j].v; int on = u.sel.cand[wv][j].n;
              rk += ((ov > cv) || (ov == cv && on < cn)) ? 1 : 0;
            }
            if (rk == k3 - 1) { u.sel.Bv[wv] = cv; u.sel.Bn[wv] = cn; }
          }
          LDS_FENCE();
          Bv = u.sel.Bv[wv]; Bn = u.sel.Bn[wv];
        }
      }
      if (fine && m > CAP) {
        // exact fallback: brute-force rank vs whole row (never on smooth data)
        keepmask = 0u;
        #pragma unroll
        for (int i = 0; i < 16; i++) {
          const int n_i = (i >> 2) * 256 + lane * 4 + (i & 3);
          const float vi = v[i];
          int rk = 0;
          for (int j = 0; j < NTOK; j++) {
            float ov = smrow[j];
            rk += ((ov > vi) || (ov == vi && j < n_i)) ? 1 : 0;
          }
          if (rk < dyn_k) keepmask |= (1u << i);
        }
      } else {
        keepmask = 0u;
        #pragma unroll
        for (int i = 0; i < 16; i++) {
          const int n_i = (i >> 2) * 256 + lane * 4 + (i & 3);
          if ((v[i] > Bv) || (v[i] == Bv && n_i <= Bn)) keepmask |= (1u << i);
        }
      }
    }
    // softmax (row max mx is always kept: rank 0 < dyn_k)
    float e[16]; float s = 0.f;
    #pragma unroll
    for (int i = 0; i < 16; i++) {
      e[i] = ((keepmask >> i) & 1u) ? __expf(v[i] - mx) : 0.f;
      s += e[i];
    }
    #pragma unroll
    for (int off = 32; off > 0; off >>= 1) s += __shfl_xor(s, off);
    if (lane == 0) invs[r] = 1.f / s;
    // write bf16 P in-place (this wave owns row r; PV reads after barrier)
    #pragma unroll
    for (int j = 0; j < 4; j++) {
      u16x4 w4 = { f2bf(e[4*j]), f2bf(e[4*j+1]), f2bf(e[4*j+2]), f2bf(e[4*j+3]) };
      *(u16x4*)&rows[r].pa[j * 256 + lane * 4] = w4;
    }
  }
  __syncthreads();

  // ---- PV via MFMA: out[8x32] = P[8x1024].V^T; 4 k-slices x 2 d-tiles ----
  {
    const int g = lane >> 4;                 // k-group 0..3
    const int m16 = lane & 15;
    const int ksl = wv & 3, dt = wv >> 2;
    const unsigned short* vrow = vbf + ((size_t)(b * 256 + h * 32 + dt * 16 + m16)) * NTOK;
    const unsigned short* parow = rows[lane & 7].pa;   // A rows 8..15 dup rows 0..7 (C rows 8..15 unused)
    f32x4 acc = {0.f, 0.f, 0.f, 0.f};
    const int nb = ksl * 256;
    #pragma unroll
    for (int ks = 0; ks < 8; ks++) {
      const int n0 = nb + ks * 32 + g * 8;
      bf16x8 a  = __builtin_bit_cast(bf16x8, *(const u16x8*)&parow[n0]);
      bf16x8 b0 = __builtin_bit_cast(bf16x8, *(const u16x8*)&vrow[n0]);
      acc = __builtin_amdgcn_mfma_f32_16x16x32_bf16(a, b0, acc, 0, 0, 0);
    }
    if (g < 2) {
      #pragma unroll
      for (int q = 0; q < 4; q++)
        u.pvred[dt][ksl][g * 4 + q][m16] = acc[q];
    }
  }
  __syncthreads();
  if (tid < 256) {
    const int r2 = tid & 7, d2 = tid >> 3;
    const int dt = d2 >> 4, m16 = d2 & 15;
    float s = u.pvred[dt][0][r2][m16] + u.pvred[dt][1][r2][m16]
            + u.pvred[dt][2][r2][m16] + u.pvred[dt][3][r2][m16];
    s *= invs[r2];
    out_attn[(size_t)(b * 256 + h * 32 + d2) * NTOK + mb * 8 + r2] = s;
  }
}

// depthwise 3x3 conv on v image + bias, fused add of attention output.
// 4 consecutive x-positions per thread with stencil reuse; OOB taps are 0.0f
// operands (fmaf(w,0,s)==s exactly) -> bit-identical to skip-logic.
__global__ __launch_bounds__(256) void pe_kernel(const float* __restrict__ qkv,
    const float* __restrict__ oattn, const float* __restrict__ pe_w,
    const float* __restrict__ pe_b, float* __restrict__ tmp) {
  int bid = blockIdx.x;
  const int c = bid & 255; const int b = bid >> 8;
  const int oc = ((c >> 5) * 64) + 32 + (c & 31);   // v channel within qkv layout
  const float* vimg = qkv + (size_t)(b * 512 + oc) * NTOK;
  float wloc[9];
  #pragma unroll
  for (int i = 0; i < 9; i++) wloc[i] = pe_w[c * 9 + i];
  const float bv = pe_b[c];
  const int t = threadIdx.x;
  const int p0 = t * 4;
  const int y = p0 >> 5, x0 = p0 & 31;
  float win[3][6];
  #pragma unroll
  for (int dy = -1; dy <= 1; dy++) {
    const int yy = y + dy;
    float* wr = win[dy + 1];
    if (yy < 0 || yy > 31) {
      #pragma unroll
      for (int i = 0; i < 6; i++) wr[i] = 0.f;
    } else {
      const float* vr = vimg + yy * 32;
      wr[0] = (x0 > 0) ? vr[x0 - 1] : 0.f;
      const float4 mid = *(const float4*)&vr[x0];
      wr[1] = mid.x; wr[2] = mid.y; wr[3] = mid.z; wr[4] = mid.w;
      wr[5] = (x0 < 28) ? vr[x0 + 4] : 0.f;
    }
  }
  const float4 oa = *(const float4*)(oattn + (size_t)(b * 256 + c) * NTOK + p0);
  float r[4];
  #pragma unroll
  for (int i = 0; i < 4; i++) {
    float s = bv;
    #pragma unroll
    for (int dy = 0; dy < 3; dy++) {
      s = fmaf(wloc[dy * 3 + 0], win[dy][i], s);
      s = fmaf(wloc[dy * 3 + 1], win[dy][i + 1], s);
      s = fmaf(wloc[dy * 3 + 2], win[dy][i + 2], s);
    }
    r[i] = s;
  }
  float4 o = make_float4(r[0] + oa.x, r[1] + oa.y, r[2] + oa.z, r[3] + oa.w);
  *(float4*)(tmp + (size_t)(b * 256 + c) * NTOK + p0) = o;
}

extern "C" void kernel_launch(void* const* d_in, const int* in_sizes, int n_in,
                              void* d_out, int out_size, void* d_ws, size_t ws_size,
                              hipStream_t stream) {
  const float* x      = (const float*)d_in[0];
  const float* qkv_w  = (const float*)d_in[1];
  const float* qkv_b  = (const float*)d_in[2];
  const float* proj_w = (const float*)d_in[3];
  const float* proj_b = (const float*)d_in[4];
  const float* pe_w   = (const float*)d_in[5];
  const float* pe_b   = (const float*)d_in[6];
  const float* g1_w   = (const float*)d_in[7];
  const float* g1_b   = (const float*)d_in[8];
  const float* g2_w   = (const float*)d_in[9];
  const float* g2_b   = (const float*)d_in[10];
  float* out = (float*)d_out;

  char* ws = (char*)d_ws;
  float*  qkvb  = (float*)(ws);                          // 8 MB
  float*  oattn = (float*)(ws + (8u << 20));             // 4 MB
  float*  tmp   = (float*)(ws + (12u << 20));            // 4 MB (pe output)
  // vbf aliases tmp[0..2MB): written by combined conv, read by attn,
  // dead before pe writes tmp (stream-ordered; R13-proven aliasing pattern).
  unsigned short* vbf = (unsigned short*)(ws + (12u << 20));   // 2 MB bf16 V
  float*  gx    = (float*)(ws + (16u << 20));            // 2 MB (gate hidden)
  double* part  = (double*)(ws + (18u << 20));           // 16 doubles

  // combined qkv + gate1 conv (gate1 rides along as extra blocks)
  qkv_gate1_kernel<<<640, 256, 0, stream>>>(x, qkv_w, qkv_b, qkvb, vbf, g1_w, g1_b, gx);
  // gate2 -> fp64 partials (dyn_k computed inside attn, deterministic)
  gate2_kernel<<<16, 256, 0, stream>>>(gx, g2_w, g2_b, part);
  // attention (exact top-dyn_k masked softmax, MFMA PV, scalar-Q logits)
  attn_kernel<<<4096, 512, 0, stream>>>(qkvb, vbf, part, oattn);
  // depthwise PE conv + add (vectorized stencil); overwrites vbf region
  pe_kernel<<<1024, 256, 0, stream>>>(qkvb, oattn, pe_w, pe_b, tmp);
  // final projection
  conv1x1_kernel<256, 4, 2, false, false><<<512, 256, 0, stream>>>(tmp, proj_w, proj_b, out, nullptr);
}

// Round 15
// 140.860 us; speedup vs baseline: 1.2495x; 1.0441x over previous
//
#include <hip/hip_runtime.h>
#include <math.h>

#define NTOK 1024
#define CAP 64

#define LDS_FENCE() asm volatile("s_waitcnt lgkmcnt(0)" ::: "memory")

typedef __bf16 bf16x8 __attribute__((ext_vector_type(8)));
typedef unsigned short u16x8 __attribute__((ext_vector_type(8)));
typedef unsigned short u16x4 __attribute__((ext_vector_type(4)));
typedef float f32x4 __attribute__((ext_vector_type(4)));

__device__ __forceinline__ unsigned short f2bf(float f) {
  unsigned int u = __float_as_uint(f);
  return (unsigned short)((u + 0x7fffu + ((u >> 16) & 1u)) >> 16);
}

// B=4, DIM=256, NH=8, HEAD_DIM=32, KEY_DIM=16, QKV_OUT=512, SCALE=0.25

// conv1x1 body (R5-proven): block-uniform weights -> scalar loads, no LDS.
// LESSON (R11): weight addressing MUST be wave-uniform (blockIdx-derived).
// LESSON (R13): don't trade VALU-issue work for longer latency chains.
template<int OC, int OCB, int P, bool RELU, bool VCAST>
__device__ __forceinline__ void conv_body(const float* __restrict__ in,
    const float* __restrict__ w, const float* __restrict__ bias, float* __restrict__ out,
    unsigned short* __restrict__ vbf, int bid, int tid) {
  constexpr int PB = NTOK / (256 * P);
  const int pb = bid % PB; bid /= PB;
  const int ocb = bid % (OC / OCB); const int b = bid / (OC / OCB);
  const int p0 = pb * 256 * P + tid * P;
  const float* inb = in + (size_t)b * 256 * NTOK + p0;
  const float* wrow = w + (size_t)ocb * OCB * 256;

  float acc[OCB][P];
  #pragma unroll
  for (int j = 0; j < OCB; j++)
    #pragma unroll
    for (int i = 0; i < P; i++) acc[j][i] = 0.f;

  #pragma unroll 2
  for (int c0 = 0; c0 < 256; c0 += 4) {
    float4 wl[OCB];
    #pragma unroll
    for (int j = 0; j < OCB; j++) wl[j] = *(const float4*)&wrow[j * 256 + c0];  // uniform -> SGPR
    #pragma unroll
    for (int cc = 0; cc < 4; cc++) {
      float xr[P];
      if constexpr (P == 4) {
        float4 t = *(const float4*)&inb[(size_t)(c0 + cc) * NTOK];
        xr[0] = t.x; xr[1] = t.y; xr[2] = t.z; xr[3] = t.w;
      } else if constexpr (P == 2) {
        float2 t = *(const float2*)&inb[(size_t)(c0 + cc) * NTOK];
        xr[0] = t.x; xr[1] = t.y;
      } else {
        xr[0] = inb[(size_t)(c0 + cc) * NTOK];
      }
      #pragma unroll
      for (int j = 0; j < OCB; j++) {
        const float wjc = ((const float*)&wl[j])[cc];
        #pragma unroll
        for (int i = 0; i < P; i++) acc[j][i] = fmaf(wjc, xr[i], acc[j][i]);
      }
    }
  }
  #pragma unroll
  for (int j = 0; j < OCB; j++) {
    const int oc = ocb * OCB + j;
    const float bv = bias[oc];
    float r[P];
    #pragma unroll
    for (int i = 0; i < P; i++) {
      float v = acc[j][i] + bv;
      if (RELU) v = fmaxf(v, 0.f);
      r[i] = v;
    }
    float* op = out + ((size_t)b * OC + oc) * NTOK + p0;
    if constexpr (P == 4) *(float4*)op = make_float4(r[0], r[1], r[2], r[3]);
    else if constexpr (P == 2) *(float2*)op = make_float2(r[0], r[1]);
    else *op = r[0];
    if constexpr (VCAST) {
      if ((oc & 63) >= 32) {
        const int c = (oc >> 6) * 32 + (oc & 63) - 32;
        unsigned short* vp = vbf + ((size_t)b * 256 + c) * NTOK + p0;
        #pragma unroll
        for (int i = 0; i < P; i++) vp[i] = f2bf(r[i]);
      }
    }
  }
}

template<int OC, int OCB, int P, bool RELU, bool VCAST>
__global__ __launch_bounds__(256) void conv1x1_kernel(const float* __restrict__ in,
    const float* __restrict__ w, const float* __restrict__ bias, float* __restrict__ out,
    unsigned short* __restrict__ vbf) {
  conv_body<OC, OCB, P, RELU, VCAST>(in, w, bias, out, vbf, blockIdx.x, threadIdx.x);
}

// Combined qkv + gate1 conv: blocks [0,512) do qkv (OC512,OCB8,P2, V-cast),
// blocks [512,640) do gate1 (OC128,OCB8,P2, RELU). Branch is block-uniform,
// weight bases stay wave-uniform.
__global__ __launch_bounds__(256) void qkv_gate1_kernel(const float* __restrict__ x,
    const float* __restrict__ qkv_w, const float* __restrict__ qkv_b, float* __restrict__ qkvb,
    unsigned short* __restrict__ vbf,
    const float* __restrict__ g1_w, const float* __restrict__ g1_b, float* __restrict__ gx) {
  const int bid = blockIdx.x;
  if (bid < 512)
    conv_body<512, 8, 2, false, true>(x, qkv_w, qkv_b, qkvb, vbf, bid, threadIdx.x);
  else
    conv_body<128, 8, 2, true, false>(x, g1_w, g1_b, gx, nullptr, bid - 512, threadIdx.x);
}

// gate2 (re-grid, 256 blocks): g[p] = sigmoid(g2_b + g2_w . relu_h[:,p]).
// Block = 16 positions x 16 j-groups; coalesced 64B-segment gx reads.
__global__ __launch_bounds__(256) void gate2_kernel(const float* __restrict__ gx,
    const float* __restrict__ g2_w, const float* __restrict__ g2_b, float* __restrict__ gvals) {
  const int tid = threadIdx.x;
  const int p_l = tid & 15, jg = tid >> 4;
  const int gp = blockIdx.x * 16 + p_l;
  const int b = gp >> 10, p = gp & 1023;
  float s = 0.f;
  const float* gb = gx + ((size_t)b * 128 + jg * 8) * NTOK + p;
  #pragma unroll
  for (int jj = 0; jj < 8; jj++) s = fmaf(g2_w[jg * 8 + jj], gb[(size_t)jj * NTOK], s);
  __shared__ float red[16][17];
  red[jg][p_l] = s;
  __syncthreads();
  if (tid < 16) {
    float a = g2_b[0];
    #pragma unroll
    for (int g = 0; g < 16; g++) a += red[g][tid];
    gvals[blockIdx.x * 16 + tid] = 1.f / (1.f + expf(-a));
  }
}

// dyn_k = clamp(floor(1024*mean(g))): deterministic fp64 (16 serial + tree-256)
__global__ void dynk_kernel(const float* __restrict__ gvals, int* __restrict__ dynk) {
  const int t = threadIdx.x;
  double s = 0.0;
  #pragma unroll
  for (int i = 0; i < 16; i++) s += (double)gvals[t + 256 * i];
  __shared__ double red[256];
  red[t] = s;
  __syncthreads();
  for (int st = 128; st > 0; st >>= 1) {
    if (t < st) red[t] += red[t + st];
    __syncthreads();
  }
  if (t == 0) {
    int k = (int)floor(1024.0 * (red[0] / 4096.0));
    *dynk = k < 1 ? 1 : (k > NTOK ? NTOK : k);
  }
}

// Attention (R12/R10-proven, verbatim; dyn_k from precomputed int): one block
// = 8 query rows of one (b,h), 512 threads, 1 row PER WAVE. Q reads
// wave-uniform -> s_load/SGPR. Exact top-dyn_k: 2-level 64-bin value radix ->
// boundary (value,index); keep = v>Bv || (v==Bv && n<=Bn) [stable-argsort
// tie rule]. PV via mfma_f32_16x16x32_bf16.
// NOTE (R8): single-pass selection (O(m)~40 serial rank) costs +28us.
// NOTE (R13): MFMA logits (split-bf16) cost +7us — latency chain beats
// the VALU-issue savings. Keep scalar-Q fp32 logits.
__global__ __launch_bounds__(512) void attn_kernel(const float* __restrict__ qkv,
    const unsigned short* __restrict__ vbf,
    const int* __restrict__ dynk_p, float* __restrict__ out_attn) {
  const int tid = threadIdx.x;
  const int lane = tid & 63, wv = tid >> 6;
  int bid = blockIdx.x;
  const int mb = bid & 127; bid >>= 7;
  const int h = bid & 7; const int b = bid >> 3;
  const int dyn_k = *dynk_p;

  const float* base = qkv + (size_t)(b * 512 + h * 64) * NTOK;

  __shared__ union RowU { float f[1028]; unsigned short pa[1032]; } rows[8];
  __shared__ float invs[8];
  __shared__ union UU {
    struct {
      int hist[8][64];
      int cnt[8];
      float Bv[8]; int Bn[8];
      struct { float v; int n; } cand[8][CAP];
    } sel;
    float pvred[2][4][8][17];
  } u;

  // ---- logits: thread computes n = 2*tid, 2*tid+1 for all 8 rows ----
  {
    const float2* k2 = (const float2*)(base + 16 * NTOK);
    const float* qb = base + mb * 8;          // q[d][r] at qb[d*NTOK + r]
    float a0[8], a1[8];
    #pragma unroll
    for (int r = 0; r < 8; r++) { a0[r] = 0.f; a1[r] = 0.f; }
    #pragma unroll
    for (int d = 0; d < 16; d++) {
      float2 kk = k2[d * 512 + tid];
      #pragma unroll
      for (int r = 0; r < 8; r++) {
        const float qv = qb[(size_t)d * NTOK + r];   // uniform -> s_load
        a0[r] = fmaf(qv, kk.x, a0[r]);
        a1[r] = fmaf(qv, kk.y, a1[r]);
      }
    }
    #pragma unroll
    for (int r = 0; r < 8; r++)
      ((float2*)rows[r].f)[tid] = make_float2(a0[r] * 0.25f, a1[r] * 0.25f);
  }
  __syncthreads();   // logits ready

  // ---- wave-local selection + softmax: wave wv owns row wv ----
  {
    const int r = wv;
    float* smrow = rows[r].f;
    float v[16];
    {
      float4 f0 = ((const float4*)smrow)[lane];
      float4 f1 = ((const float4*)smrow)[64 + lane];
      float4 f2 = ((const float4*)smrow)[128 + lane];
      float4 f3 = ((const float4*)smrow)[192 + lane];
      v[0]=f0.x; v[1]=f0.y; v[2]=f0.z; v[3]=f0.w;
      v[4]=f1.x; v[5]=f1.y; v[6]=f1.z; v[7]=f1.w;
      v[8]=f2.x; v[9]=f2.y; v[10]=f2.z; v[11]=f2.w;
      v[12]=f3.x; v[13]=f3.y; v[14]=f3.z; v[15]=f3.w;
    }
    float mn = v[0], mx = v[0];
    #pragma unroll
    for (int i = 1; i < 16; i++) { mn = fminf(mn, v[i]); mx = fmaxf(mx, v[i]); }
    #pragma unroll
    for (int off = 32; off > 0; off >>= 1) {
      mn = fminf(mn, __shfl_xor(mn, off));
      mx = fmaxf(mx, __shfl_xor(mx, off));
    }

    unsigned int keepmask = 0xFFFFu;
    if (dyn_k < NTOK) {
      float Bv = mx; int Bn = dyn_k - 1;        // degenerate (all-equal) default
      const float range = mx - mn;
      const bool fine = (range > 0.f);
      int m = 0;
      if (fine) {
        const float s1 = 64.0f / range;
        // pass 1: 64 bins over [mn,mx]
        u.sel.hist[wv][lane] = 0;
        LDS_FENCE();
        int idx1[16];
        #pragma unroll
        for (int i = 0; i < 16; i++) {
          int ix = (int)((v[i] - mn) * s1);
          ix = ix < 0 ? 0 : (ix > 63 ? 63 : ix);
          idx1[i] = ix;
          atomicAdd(&u.sel.hist[wv][ix], 1);
        }
        LDS_FENCE();
        int cum = u.sel.hist[wv][lane];
        #pragma unroll
        for (int off = 1; off < 64; off <<= 1) {
          int o = __shfl_down(cum, off);
          if (lane + off < 64) cum += o;
        }
        int cumNext = __shfl_down(cum, 1);
        if (lane == 63) cumNext = 0;
        unsigned long long bal = __ballot(cum >= dyn_k && cumNext < dyn_k);
        const int t = (int)__builtin_ctzll(bal);
        const int k2 = dyn_k - __shfl(cumNext, t);
        // pass 2: 64 sub-bins within bin t
        const float binw = range * (1.0f / 64.0f);
        const float lo = mn + (float)t * binw;
        float s2 = 4096.0f / range;
        if (!(s2 < 3.0e38f)) s2 = 0.f;
        u.sel.hist[wv][lane] = 0;
        LDS_FENCE();
        #pragma unroll
        for (int i = 0; i < 16; i++) {
          if (idx1[i] == t) {
            int ix = (int)((v[i] - lo) * s2);
            ix = ix < 0 ? 0 : (ix > 63 ? 63 : ix);
            atomicAdd(&u.sel.hist[wv][ix], 1);
          }
        }
        LDS_FENCE();
        cum = u.sel.hist[wv][lane];
        #pragma unroll
        for (int off = 1; off < 64; off <<= 1) {
          int o = __shfl_down(cum, off);
          if (lane + off < 64) cum += o;
        }
        cumNext = __shfl_down(cum, 1);
        if (lane == 63) cumNext = 0;
        bal = __ballot(cum >= k2 && cumNext < k2);
        const int t2 = (int)__builtin_ctzll(bal);
        const int k3 = k2 - __shfl(cumNext, t2);
        // collect candidates in sub-bin (t,t2)
        if (lane == 0) u.sel.cnt[wv] = 0;
        LDS_FENCE();
        #pragma unroll
        for (int i = 0; i < 16; i++) {
          if (idx1[i] == t) {
            int ix = (int)((v[i] - lo) * s2);
            ix = ix < 0 ? 0 : (ix > 63 ? 63 : ix);
            if (ix == t2) {
              int p = atomicAdd(&u.sel.cnt[wv], 1);
              if (p < CAP) { u.sel.cand[wv][p].v = v[i]; u.sel.cand[wv][p].n = (i >> 2) * 256 + lane * 4 + (i & 3); }
            }
          }
        }
        LDS_FENCE();
        m = u.sel.cnt[wv];
        if (m <= CAP) {
          // exact boundary element: rank k3-1 among candidates (value desc, idx asc)
          for (int ii = lane; ii < m; ii += 64) {
            float cv = u.sel.cand[wv][ii].v; int cn = u.sel.cand[wv][ii].n;
            int rk = 0;
            for (int j = 0; j < m; j++) {
              float ov = u.sel.cand[wv][j].v; int on = u.sel.cand[wv][j].n;
              rk += ((ov > cv) || (ov == cv && on < cn)) ? 1 : 0;
            }
            if (rk == k3 - 1) { u.sel.Bv[wv] = cv; u.sel.Bn[wv] = cn; }
          }
          LDS_FENCE();
          Bv = u.sel.Bv[wv]; Bn = u.sel.Bn[wv];
        }
      }
      if (fine && m > CAP) {
        // exact fallback: brute-force rank vs whole row (never on smooth data)
        keepmask = 0u;
        #pragma unroll
        for (int i = 0; i < 16; i++) {
          const int n_i = (i >> 2) * 256 + lane * 4 + (i & 3);
          const float vi = v[i];
          int rk = 0;
          for (int j = 0; j < NTOK; j++) {
            float ov = smrow[j];
            rk += ((ov > vi) || (ov == vi && j < n_i)) ? 1 : 0;
          }
          if (rk < dyn_k) keepmask |= (1u << i);
        }
      } else {
        keepmask = 0u;
        #pragma unroll
        for (int i = 0; i < 16; i++) {
          const int n_i = (i >> 2) * 256 + lane * 4 + (i & 3);
          if ((v[i] > Bv) || (v[i] == Bv && n_i <= Bn)) keepmask |= (1u << i);
        }
      }
    }
    // softmax (row max mx is always kept: rank 0 < dyn_k)
    float e[16]; float s = 0.f;
    #pragma unroll
    for (int i = 0; i < 16; i++) {
      e[i] = ((keepmask >> i) & 1u) ? __expf(v[i] - mx) : 0.f;
      s += e[i];
    }
    #pragma unroll
    for (int off = 32; off > 0; off >>= 1) s += __shfl_xor(s, off);
    if (lane == 0) invs[r] = 1.f / s;
    // write bf16 P in-place (this wave owns row r; PV reads after barrier)
    #pragma unroll
    for (int j = 0; j < 4; j++) {
      u16x4 w4 = { f2bf(e[4*j]), f2bf(e[4*j+1]), f2bf(e[4*j+2]), f2bf(e[4*j+3]) };
      *(u16x4*)&rows[r].pa[j * 256 + lane * 4] = w4;
    }
  }
  __syncthreads();

  // ---- PV via MFMA: out[8x32] = P[8x1024].V^T; 4 k-slices x 2 d-tiles ----
  {
    const int g = lane >> 4;                 // k-group 0..3
    const int m16 = lane & 15;
    const int ksl = wv & 3, dt = wv >> 2;
    const unsigned short* vrow = vbf + ((size_t)(b * 256 + h * 32 + dt * 16 + m16)) * NTOK;
    const unsigned short* parow = rows[lane & 7].pa;   // A rows 8..15 dup rows 0..7 (C rows 8..15 unused)
    f32x4 acc = {0.f, 0.f, 0.f, 0.f};
    const int nb = ksl * 256;
    #pragma unroll
    for (int ks = 0; ks < 8; ks++) {
      const int n0 = nb + ks * 32 + g * 8;
      bf16x8 a  = __builtin_bit_cast(bf16x8, *(const u16x8*)&parow[n0]);
      bf16x8 b0 = __builtin_bit_cast(bf16x8, *(const u16x8*)&vrow[n0]);
      acc = __builtin_amdgcn_mfma_f32_16x16x32_bf16(a, b0, acc, 0, 0, 0);
    }
    if (g < 2) {
      #pragma unroll
      for (int q = 0; q < 4; q++)
        u.pvred[dt][ksl][g * 4 + q][m16] = acc[q];
    }
  }
  __syncthreads();
  if (tid < 256) {
    const int r2 = tid & 7, d2 = tid >> 3;
    const int dt = d2 >> 4, m16 = d2 & 15;
    float s = u.pvred[dt][0][r2][m16] + u.pvred[dt][1][r2][m16]
            + u.pvred[dt][2][r2][m16] + u.pvred[dt][3][r2][m16];
    s *= invs[r2];
    out_attn[(size_t)(b * 256 + h * 32 + d2) * NTOK + mb * 8 + r2] = s;
  }
}

// depthwise 3x3 conv on v image + bias, fused add of attention output.
// 4 consecutive x-positions per thread with stencil reuse; OOB taps are 0.0f
// operands (fmaf(w,0,s)==s exactly) -> bit-identical to skip-logic.
__global__ __launch_bounds__(256) void pe_kernel(const float* __restrict__ qkv,
    const float* __restrict__ oattn, const float* __restrict__ pe_w,
    const float* __restrict__ pe_b, float* __restrict__ tmp) {
  int bid = blockIdx.x;
  const int c = bid & 255; const int b = bid >> 8;
  const int oc = ((c >> 5) * 64) + 32 + (c & 31);   // v channel within qkv layout
  const float* vimg = qkv + (size_t)(b * 512 + oc) * NTOK;
  float wloc[9];
  #pragma unroll
  for (int i = 0; i < 9; i++) wloc[i] = pe_w[c * 9 + i];
  const float bv = pe_b[c];
  const int t = threadIdx.x;
  const int p0 = t * 4;
  const int y = p0 >> 5, x0 = p0 & 31;
  float win[3][6];
  #pragma unroll
  for (int dy = -1; dy <= 1; dy++) {
    const int yy = y + dy;
    float* wr = win[dy + 1];
    if (yy < 0 || yy > 31) {
      #pragma unroll
      for (int i = 0; i < 6; i++) wr[i] = 0.f;
    } else {
      const float* vr = vimg + yy * 32;
      wr[0] = (x0 > 0) ? vr[x0 - 1] : 0.f;
      const float4 mid = *(const float4*)&vr[x0];
      wr[1] = mid.x; wr[2] = mid.y; wr[3] = mid.z; wr[4] = mid.w;
      wr[5] = (x0 < 28) ? vr[x0 + 4] : 0.f;
    }
  }
  const float4 oa = *(const float4*)(oattn + (size_t)(b * 256 + c) * NTOK + p0);
  float r[4];
  #pragma unroll
  for (int i = 0; i < 4; i++) {
    float s = bv;
    #pragma unroll
    for (int dy = 0; dy < 3; dy++) {
      s = fmaf(wloc[dy * 3 + 0], win[dy][i], s);
      s = fmaf(wloc[dy * 3 + 1], win[dy][i + 1], s);
      s = fmaf(wloc[dy * 3 + 2], win[dy][i + 2], s);
    }
    r[i] = s;
  }
  float4 o = make_float4(r[0] + oa.x, r[1] + oa.y, r[2] + oa.z, r[3] + oa.w);
  *(float4*)(tmp + (size_t)(b * 256 + c) * NTOK + p0) = o;
}

extern "C" void kernel_launch(void* const* d_in, const int* in_sizes, int n_in,
                              void* d_out, int out_size, void* d_ws, size_t ws_size,
                              hipStream_t stream) {
  const float* x      = (const float*)d_in[0];
  const float* qkv_w  = (const float*)d_in[1];
  const float* qkv_b  = (const float*)d_in[2];
  const float* proj_w = (const float*)d_in[3];
  const float* proj_b = (const float*)d_in[4];
  const float* pe_w   = (const float*)d_in[5];
  const float* pe_b   = (const float*)d_in[6];
  const float* g1_w   = (const float*)d_in[7];
  const float* g1_b   = (const float*)d_in[8];
  const float* g2_w   = (const float*)d_in[9];
  const float* g2_b   = (const float*)d_in[10];
  float* out = (float*)d_out;

  char* ws = (char*)d_ws;
  float*  qkvb  = (float*)(ws);                          // 8 MB
  float*  oattn = (float*)(ws + (8u << 20));             // 4 MB
  float*  tmp   = (float*)(ws + (12u << 20));            // 4 MB (pe output)
  // vbf aliases tmp[0..2MB): written by combined conv, read by attn,
  // dead before pe writes tmp (stream-ordered; R13/R14-proven pattern).
  unsigned short* vbf = (unsigned short*)(ws + (12u << 20));   // 2 MB bf16 V
  float*  gx    = (float*)(ws + (16u << 20));            // 2 MB (gate hidden)
  float*  gvals = (float*)(ws + (18u << 20));            // 16 KB per-pos gate
  int*    dynk  = (int*)(ws + (18u << 20) + (64u << 10));

  // combined qkv + gate1 conv (gate1 rides along as extra blocks)
  qkv_gate1_kernel<<<640, 256, 0, stream>>>(x, qkv_w, qkv_b, qkvb, vbf, g1_w, g1_b, gx);
  // gate2 (256 blocks, coalesced) -> per-position g, then 1-block fp64 dyn_k
  gate2_kernel<<<256, 256, 0, stream>>>(gx, g2_w, g2_b, gvals);
  dynk_kernel<<<1, 256, 0, stream>>>(gvals, dynk);
  // attention (exact top-dyn_k masked softmax, MFMA PV, scalar-Q logits)
  attn_kernel<<<4096, 512, 0, stream>>>(qkvb, vbf, dynk, oattn);
  // depthwise PE conv + add (vectorized stencil); overwrites vbf region
  pe_kernel<<<1024, 256, 0, stream>>>(qkvb, oattn, pe_w, pe_b, tmp);
  // final projection (OCB8/P1: halves x re-read traffic, same 512-block grid)
  conv1x1_kernel<256, 8, 1, false, false><<<512, 256, 0, stream>>>(tmp, proj_w, proj_b, out, nullptr);
}